// Round 8
// baseline (152.007 us; speedup 1.0000x reference)
//
#include <hip/hip_runtime.h>
#include <math.h>

#define MAXT 100000.0f
#define EPSILON 1e-10f
#define M_OUT 1024
#define BATCH 64
#define PITCH 1028      // sorted-row pitch: 1025 real + 3 pad
#define ROWS 32         // W rows per staged chunk
#define NCH 32          // chunks cover k = 0..1023; k = 1024 in epilogue

#define WAIT_VM32() asm volatile("s_waitcnt vmcnt(32)" ::: "memory")
#define WAIT_VM0()  asm volatile("s_waitcnt vmcnt(0)"  ::: "memory")
#define SCHED_WALL() __builtin_amdgcn_sched_barrier(0)

// ---------------------------------------------------------------------------
// Kernel 1: stable rank via branchless u64 keys in LDS (all-pairs).
// key = (float_bits(x) << 11) | index — positive floats order as bit patterns,
// low bits give the stable (j < i) argsort tie-break exactly. Dual accumulators
// shorten the addc dependence chain. Also rewrites pads sx[1025..1027]=MAXT,
// soff[..]=0 every launch (ws is re-poisoned 0xAA).
// ---------------------------------------------------------------------------
__global__ __launch_bounds__(256) void rank_kernel(const float* __restrict__ X,
                                                   float* __restrict__ sx,
                                                   int* __restrict__ soff) {
    const int b = blockIdx.y;
    const int tid = threadIdx.x;
    __shared__ __align__(16) unsigned long long keys[1028];
    for (int i = tid; i < 1028; i += 256) {
        float v;
        if (i < 1024)       v = X[b * 1024 + i];
        else if (i == 1024) v = 1.0f;                     // bias spike time
        else                v = __builtin_huge_valf();    // rank-neutral pad
        keys[i] = ((unsigned long long)__float_as_uint(v) << 11) | (unsigned)i;
    }
    __syncthreads();

    const int i = blockIdx.x * 256 + tid;
    if (i > 1024) {
        if (i < PITCH) { sx[b * PITCH + i] = MAXT; soff[b * PITCH + i] = 0; }
        return;
    }
    const unsigned long long ki = keys[i];
    int ra = 0, rb = 0;
#pragma unroll 8
    for (int j = 0; j < 1028; j += 4) {
        const ulonglong2 k0 = *(const ulonglong2*)&keys[j];
        const ulonglong2 k1 = *(const ulonglong2*)&keys[j + 2];
        ra += (int)(k0.x < ki); ra += (int)(k0.y < ki);
        rb += (int)(k1.x < ki); rb += (int)(k1.y < ki);
    }
    const int rank = ra + rb;
    sx[b * PITCH + rank]   = __uint_as_float((unsigned)(ki >> 11));
    soff[b * PITCH + rank] = (int)(ki & 2047u) * 4096;    // byte offset into W
}

// ---------------------------------------------------------------------------
// Kernel 2: sequential scan, one thread per (b, m). W gathered in sorted-row
// order into WAVE-PRIVATE LDS via global_load_lds (no VGPR staging -> nothing
// for the scheduler to collapse; R3-R5 failure mode), double-buffered, synced
// per-wave with manual s_waitcnt vmcnt(32) — zero barriers in the main loop.
// off/xs staged to LDS up front so the ONLY vmcnt ops in the loop are the
// global_load_lds themselves (exact counting). Division-free validity/min;
// one IEEE div at the end reproduces the ref's fl(cwt/denom). cw/cwt are
// bit-identical to numpy (__fadd_rn/__fmul_rn, no FMA contraction).
// ---------------------------------------------------------------------------
#define SNN_STEP(kk, wval)                                                     \
    {                                                                          \
        const float x  = xs_s[(kk)];                                           \
        const float xn = xs_s[(kk) + 1];                                       \
        const float w  = (wval);                                               \
        cw  = __fadd_rn(cw, w);                                                \
        cwt = __fadd_rn(cwt, __fmul_rn(w, x));                                 \
        const float denom = fmaxf(__fadd_rn(cw, -1.0f), EPSILON);              \
        const bool valid = (cw >= 1.0f)                                        \
                         & (cwt >= __fmul_rn(x, denom))                        \
                         & (cwt <= __fmul_rn(xn, denom));                      \
        const bool better = valid                                              \
                          & (__fmul_rn(cwt, bd) < __fmul_rn(bn, denom));       \
        bn = better ? cwt   : bn;                                              \
        bd = better ? denom : bd;                                              \
    }

__global__ __launch_bounds__(256, 1) void snn_scan(const float* __restrict__ W,
                                                   const float* __restrict__ sx,
                                                   const int* __restrict__ soff,
                                                   float* __restrict__ out) {
    const int b    = blockIdx.y;
    const int tid  = threadIdx.x;
    const int wave = tid >> 6;
    const int lane = tid & 63;
    const int m    = blockIdx.x * 256 + tid;

    __shared__ __align__(16) float xs_s[PITCH];
    __shared__ __align__(16) int   off_s[PITCH];
    __shared__ __align__(16) float wbuf[2][4][ROWS * 64];   // 64 KB, wave-private regions

    const float* sxb = sx + b * PITCH;
    const int*   sob = soff + b * PITCH;
    for (int i = tid; i < PITCH; i += 256) { xs_s[i] = sxb[i]; off_s[i] = sob[i]; }
    __syncthreads();   // drains vmcnt to 0 -> manual counting below is exact

    // wave's 64-column base into W (bytes)
    const char* Wbase = (const char*)W + (size_t)(blockIdx.x * 256 + wave * 64) * 4;

    float cw = 0.0f, cwt = 0.0f;
    float bn = MAXT, bd = 1.0f;

    // stage chunk c (rows c*32 .. c*32+31, this wave's 64 cols) into buffer p.
    // 32 global_load_lds(size=4): dest = uniform lds base + lane*4.
    auto stage = [&](int c, int p) {
        const int k0 = c * ROWS;
        float* ldsrow = &wbuf[p][wave][0];
#pragma unroll
        for (int r4 = 0; r4 < ROWS / 4; ++r4) {
            const int4 o = *(const int4*)&off_s[k0 + r4 * 4];   // ds_read_b128, uniform
            const float* g0 = (const float*)(Wbase + o.x) + lane;
            const float* g1 = (const float*)(Wbase + o.y) + lane;
            const float* g2 = (const float*)(Wbase + o.z) + lane;
            const float* g3 = (const float*)(Wbase + o.w) + lane;
            __builtin_amdgcn_global_load_lds((const __attribute__((address_space(1))) void*)g0,
                (__attribute__((address_space(3))) void*)(ldsrow + (r4 * 4 + 0) * 64), 4, 0, 0);
            __builtin_amdgcn_global_load_lds((const __attribute__((address_space(1))) void*)g1,
                (__attribute__((address_space(3))) void*)(ldsrow + (r4 * 4 + 1) * 64), 4, 0, 0);
            __builtin_amdgcn_global_load_lds((const __attribute__((address_space(1))) void*)g2,
                (__attribute__((address_space(3))) void*)(ldsrow + (r4 * 4 + 2) * 64), 4, 0, 0);
            __builtin_amdgcn_global_load_lds((const __attribute__((address_space(1))) void*)g3,
                (__attribute__((address_space(3))) void*)(ldsrow + (r4 * 4 + 3) * 64), 4, 0, 0);
        }
    };

    auto compute = [&](int c, int p) {
        const int k0 = c * ROWS;
        const float* ldsrow = &wbuf[p][wave][0];
#pragma unroll
        for (int u = 0; u < ROWS; ++u) {
            const float wv = ldsrow[u * 64 + lane];   // 2-way bank alias = free
            SNN_STEP(k0 + u, wv);
        }
    };

    stage(0, 0);
    stage(1, 1);
    SCHED_WALL();

    for (int c = 0; c < NCH - 2; ++c) {
        WAIT_VM32();          // chunk c's 32 loads landed; chunk c+1 may be in flight
        SCHED_WALL();
        compute(c, c & 1);
        SCHED_WALL();
        stage(c + 2, c & 1);  // refill the buffer just consumed
        SCHED_WALL();
    }
    WAIT_VM32(); SCHED_WALL();
    compute(NCH - 2, (NCH - 2) & 1);
    WAIT_VM0();  SCHED_WALL();
    compute(NCH - 1, (NCH - 1) & 1);
    SCHED_WALL();

    // epilogue: k = 1024 (plain load; all LDS-DMA drained, compiler manages wait)
    const float w1024 = *(const float*)((const char*)W + off_s[1024] + (size_t)m * 4);
    SNN_STEP(1024, w1024);

    out[b * M_OUT + m] = bn / bd;   // single IEEE div == ref's fl(cwt/denom)
}

extern "C" void kernel_launch(void* const* d_in, const int* in_sizes, int n_in,
                              void* d_out, int out_size, void* d_ws, size_t ws_size,
                              hipStream_t stream) {
    const float* X = (const float*)d_in[0];   // [64, 1024]
    const float* W = (const float*)d_in[1];   // [1025, 1024]
    float* out = (float*)d_out;               // [64, 1024]

    float* sx   = (float*)d_ws;                                        // [64, PITCH]
    int*   soff = (int*)((char*)d_ws + BATCH * PITCH * sizeof(float)); // [64, PITCH]

    dim3 g1(5, BATCH);
    rank_kernel<<<g1, 256, 0, stream>>>(X, sx, soff);

    dim3 g2(M_OUT / 256, BATCH);
    snn_scan<<<g2, 256, 0, stream>>>(W, sx, soff, out);
}

// Round 9
// 103.363 us; speedup vs baseline: 1.4706x; 1.4706x over previous
//
#include <hip/hip_runtime.h>
#include <math.h>

#define MAXT 100000.0f
#define EPSILON 1e-10f
#define M_OUT 1024
#define BATCH 64
#define PITCH 1028      // sorted arrays: 1025 real + 3 pad
#define NSEG 16
#define SEGLEN 64

// ---------------------------------------------------------------------------
// Kernel 1: stable rank via u32 keys (21 mantissa bits || 11 index bits).
// X in [1,2): bits-0x3F800000 fits 23 bits; >>2 keeps 21 (4-ulp ties fall to
// the index order = adjacent-swap perturbation, compensated by the scan's
// boundary algebra). Keys strictly unique (index bits) -> rank is a perm.
// Halves R8's LDS traffic (rank was LDS-b128-throughput-bound at ~18 us).
// Writes TRUE x to sx (keys are lossy), byte row offsets to soff, pads every
// launch (ws re-poisoned 0xAA).
// ---------------------------------------------------------------------------
__global__ __launch_bounds__(256) void rank_kernel(const float* __restrict__ X,
                                                   float* __restrict__ sx,
                                                   int* __restrict__ soff) {
    const int b = blockIdx.y;
    const int tid = threadIdx.x;
    __shared__ __align__(16) unsigned keys[1032];

    float myx = 1.0f;   // i == 1024 (bias) keeps this default
#pragma unroll
    for (int c = 0; c < 4; ++c) {
        const int i = c * 256 + tid;
        const float v = X[b * 1024 + i];
        keys[i] = (((__float_as_uint(v) - 0x3F800000u) >> 2) << 11) | (unsigned)i;
        if (c == blockIdx.x) myx = v;
    }
    if (tid == 0) keys[1024] = 1024u;                       // bias: mantissa 0 | idx 1024
    else if (tid < 8) keys[1024 + tid] = 0xFFFFFFFFu;       // pads: > all real keys
    __syncthreads();

    const int i = blockIdx.x * 256 + tid;
    if (i > 1024) {
        if (i < PITCH) { sx[b * PITCH + i] = MAXT; soff[b * PITCH + i] = 0; }
        return;
    }
    const unsigned ki = keys[i];
    int r0 = 0, r1 = 0;
#pragma unroll 8
    for (int j = 0; j < 1032; j += 8) {
        const uint4 a = *(const uint4*)&keys[j];
        const uint4 c = *(const uint4*)&keys[j + 4];
        r0 += (int)(a.x < ki) + (int)(a.y < ki) + (int)(a.z < ki) + (int)(a.w < ki);
        r1 += (int)(c.x < ki) + (int)(c.y < ki) + (int)(c.z < ki) + (int)(c.w < ki);
    }
    const int rank = r0 + r1;
    sx[b * PITCH + rank]   = myx;
    soff[b * PITCH + rank] = i * 4096;                      // byte offset into W
}

// ---------------------------------------------------------------------------
// Kernel 2: decoupled two-pass K-scan in one 1024-thread block.
// Wave w (of 16) owns k-segment [w*64, w*64+64); lane owns 4 consecutive
// columns (float4 W loads). Pass 1: segment sums (left-to-right fadd within
// segment). LDS exchange -> exclusive prefix (ascending-s fadd). Pass 2: full
// validity scan of own segment from that prefix. 16 waves/CU = 4/SIMD TLP +
// 4 independent accumulator chains/lane: no replay (R7), no 1-wave latency
// wall (R2-R8). Validity/min division-free (cross-multiply, validated since
// R3); one IEEE div per segment; cross-segment fminf reduce in LDS.
// ---------------------------------------------------------------------------
#define SNN_STEP_J(j, xx, xxn, wv)                                             \
    {                                                                          \
        cw[j]  = __fadd_rn(cw[j], (wv));                                       \
        cwt[j] = __fadd_rn(cwt[j], __fmul_rn((wv), (xx)));                     \
        const float denom = fmaxf(__fadd_rn(cw[j], -1.0f), EPSILON);           \
        const bool valid = (cw[j] >= 1.0f)                                     \
                         & (cwt[j] >= __fmul_rn((xx), denom))                  \
                         & (cwt[j] <= __fmul_rn((xxn), denom));                \
        const bool better = valid                                              \
                          & (__fmul_rn(cwt[j], bd[j]) < __fmul_rn(bn[j], denom)); \
        bn[j] = better ? cwt[j] : bn[j];                                       \
        bd[j] = better ? denom  : bd[j];                                       \
    }

__global__ __launch_bounds__(1024, 1) void snn_scan(const float* __restrict__ W,
                                                    const float* __restrict__ sx,
                                                    const int* __restrict__ soff,
                                                    float* __restrict__ out) {
    const int b    = blockIdx.y;
    const int tid  = threadIdx.x;
    const int w    = tid >> 6;        // wave = K-segment id, 0..15
    const int lane = tid & 63;
    const int mq   = blockIdx.x * 256 + lane * 4;   // this lane's column quad

    __shared__ __align__(16) float xs_s[PITCH];
    __shared__ __align__(16) int   off_s[PITCH];
    __shared__ __align__(16) float segw [NSEG][256];
    __shared__ __align__(16) float segwt[NSEG][256];
    __shared__ __align__(16) float best [NSEG][256];

    xs_s[tid]  = sx[b * PITCH + tid];
    off_s[tid] = soff[b * PITCH + tid];
    if (tid < 4) {
        xs_s[1024 + tid]  = sx[b * PITCH + 1024 + tid];
        off_s[1024 + tid] = soff[b * PITCH + 1024 + tid];
    }
    __syncthreads();

    const char* Wq = (const char*)W + (size_t)mq * 4;
    const int k0 = w * SEGLEN;

    // ---- pass 1: segment sums (ascending k, left-to-right fadd) ----
    float cw[4] = {0, 0, 0, 0}, cwt[4] = {0, 0, 0, 0};
    for (int k = k0; k < k0 + SEGLEN; k += 4) {
        const int4 o = *(const int4*)&off_s[k];            // 16B-aligned (k%4==0)
        const float4 wa = *(const float4*)(Wq + o.x);
        const float4 wb = *(const float4*)(Wq + o.y);
        const float4 wc = *(const float4*)(Wq + o.z);
        const float4 wd = *(const float4*)(Wq + o.w);
        const float xa = xs_s[k], xb = xs_s[k + 1], xc = xs_s[k + 2], xd = xs_s[k + 3];
        const float wv0[4] = {wa.x, wa.y, wa.z, wa.w};
        const float wv1[4] = {wb.x, wb.y, wb.z, wb.w};
        const float wv2[4] = {wc.x, wc.y, wc.z, wc.w};
        const float wv3[4] = {wd.x, wd.y, wd.z, wd.w};
#pragma unroll
        for (int j = 0; j < 4; ++j) { cw[j] = __fadd_rn(cw[j], wv0[j]); cwt[j] = __fadd_rn(cwt[j], __fmul_rn(wv0[j], xa)); }
#pragma unroll
        for (int j = 0; j < 4; ++j) { cw[j] = __fadd_rn(cw[j], wv1[j]); cwt[j] = __fadd_rn(cwt[j], __fmul_rn(wv1[j], xb)); }
#pragma unroll
        for (int j = 0; j < 4; ++j) { cw[j] = __fadd_rn(cw[j], wv2[j]); cwt[j] = __fadd_rn(cwt[j], __fmul_rn(wv2[j], xc)); }
#pragma unroll
        for (int j = 0; j < 4; ++j) { cw[j] = __fadd_rn(cw[j], wv3[j]); cwt[j] = __fadd_rn(cwt[j], __fmul_rn(wv3[j], xd)); }
    }
    *(float4*)&segw[w][lane * 4]  = make_float4(cw[0], cw[1], cw[2], cw[3]);
    *(float4*)&segwt[w][lane * 4] = make_float4(cwt[0], cwt[1], cwt[2], cwt[3]);
    __syncthreads();

    // ---- exclusive prefix over segments (ascending s) ----
#pragma unroll
    for (int j = 0; j < 4; ++j) { cw[j] = 0.0f; cwt[j] = 0.0f; }
    for (int s = 0; s < w; ++s) {                          // wave-uniform trip count
        const float4 a = *(const float4*)&segw[s][lane * 4];
        const float4 t = *(const float4*)&segwt[s][lane * 4];
        cw[0] = __fadd_rn(cw[0], a.x); cw[1] = __fadd_rn(cw[1], a.y);
        cw[2] = __fadd_rn(cw[2], a.z); cw[3] = __fadd_rn(cw[3], a.w);
        cwt[0] = __fadd_rn(cwt[0], t.x); cwt[1] = __fadd_rn(cwt[1], t.y);
        cwt[2] = __fadd_rn(cwt[2], t.z); cwt[3] = __fadd_rn(cwt[3], t.w);
    }

    // ---- pass 2: full validity scan of own segment ----
    float bn[4] = {MAXT, MAXT, MAXT, MAXT}, bd[4] = {1.0f, 1.0f, 1.0f, 1.0f};
    for (int k = k0; k < k0 + SEGLEN; k += 4) {
        const int4 o = *(const int4*)&off_s[k];
        const float4 wa = *(const float4*)(Wq + o.x);
        const float4 wb = *(const float4*)(Wq + o.y);
        const float4 wc = *(const float4*)(Wq + o.z);
        const float4 wd = *(const float4*)(Wq + o.w);
        const float xa = xs_s[k],     xan = xs_s[k + 1];
        const float xb = xs_s[k + 1], xbn = xs_s[k + 2];
        const float xc = xs_s[k + 2], xcn = xs_s[k + 3];
        const float xd = xs_s[k + 3], xdn = xs_s[k + 4];
        const float wv0[4] = {wa.x, wa.y, wa.z, wa.w};
        const float wv1[4] = {wb.x, wb.y, wb.z, wb.w};
        const float wv2[4] = {wc.x, wc.y, wc.z, wc.w};
        const float wv3[4] = {wd.x, wd.y, wd.z, wd.w};
#pragma unroll
        for (int j = 0; j < 4; ++j) SNN_STEP_J(j, xa, xan, wv0[j]);
#pragma unroll
        for (int j = 0; j < 4; ++j) SNN_STEP_J(j, xb, xbn, wv1[j]);
#pragma unroll
        for (int j = 0; j < 4; ++j) SNN_STEP_J(j, xc, xcn, wv2[j]);
#pragma unroll
        for (int j = 0; j < 4; ++j) SNN_STEP_J(j, xd, xdn, wv3[j]);
    }
    if (w == NSEG - 1) {   // epilogue: k = 1024 (xn = pad MAXT)
        const float4 we = *(const float4*)(Wq + off_s[1024]);
        const float xe = xs_s[1024], xen = xs_s[1025];
        const float wve[4] = {we.x, we.y, we.z, we.w};
#pragma unroll
        for (int j = 0; j < 4; ++j) SNN_STEP_J(j, xe, xen, wve[j]);
    }

    // per-segment result + cross-segment min
    *(float4*)&best[w][lane * 4] = make_float4(bn[0] / bd[0], bn[1] / bd[1],
                                               bn[2] / bd[2], bn[3] / bd[3]);
    __syncthreads();
    if (tid < 256) {
        float r = best[0][tid];
#pragma unroll
        for (int s = 1; s < NSEG; ++s) r = fminf(r, best[s][tid]);
        out[b * M_OUT + blockIdx.x * 256 + tid] = r;
    }
}

extern "C" void kernel_launch(void* const* d_in, const int* in_sizes, int n_in,
                              void* d_out, int out_size, void* d_ws, size_t ws_size,
                              hipStream_t stream) {
    const float* X = (const float*)d_in[0];   // [64, 1024]
    const float* W = (const float*)d_in[1];   // [1025, 1024]
    float* out = (float*)d_out;               // [64, 1024]

    float* sx   = (float*)d_ws;                                        // [64, PITCH]
    int*   soff = (int*)((char*)d_ws + BATCH * PITCH * sizeof(float)); // [64, PITCH]

    dim3 g1(5, BATCH);
    rank_kernel<<<g1, 256, 0, stream>>>(X, sx, soff);

    dim3 g2(M_OUT / 256, BATCH);
    snn_scan<<<g2, 1024, 0, stream>>>(W, sx, soff, out);
}